// Round 15
// baseline (286.002 us; speedup 1.0000x reference)
//
#include <hip/hip_runtime.h>
#include <hip/hip_bf16.h>
#include <math.h>

#define E_DIM    64
#define N_EMBED  1024
#define N_TOKENS 262144
#define FQCAP    32768

typedef __attribute__((ext_vector_type(8)))  short bf16x8;
typedef __attribute__((ext_vector_type(16))) float f32x16;

// ---------------------------------------------------------------------------
// Reference semantics (verified absmax 0.0 rounds 2,3,5,6,8-14): f32 numpy
// mirror:  b_j single fmaf chain ascending k;  a AVX512-pairwise;
// c_j sequential;  dist = fl(fl(a-2b)+c);  argmin first-min-wins.
// Round 15 = round 14 with the LDS round-trip DELETED: prep writes eTc in a
// fragment-major layout [chunk][frag=(tp*4+s)*4+{hiA,loA,hiB,loB}][lane], so
// each MFMA A-operand is ONE coalesced global_load_dwordx4 from the
// L2-resident 256 KB buffer. No __shared__, no barriers, no LDS-pipe
// serialization; occupancy no longer LDS-capped. Operand values and MFMA
// order are bit-identical to r14.
// ---------------------------------------------------------------------------

__device__ __forceinline__ short f2bf_bits(float f) {
    __hip_bfloat16 h = __float2bfloat16(f);
    return *reinterpret_cast<short*>(&h);
}
__device__ __forceinline__ float bfbits2f(short s) {
    unsigned int u = ((unsigned int)(unsigned short)s) << 16;
    return __uint_as_float(u);
}

// exact replica of one dist entry: d = fl(fl(a-2b)+c), b = fmaf chain asc k
__device__ __forceinline__ float exact_d(const float* __restrict__ xrow,
                                         const float* __restrict__ emb,
                                         const float* __restrict__ csum,
                                         float a, int j) {
#pragma clang fp contract(off)
    float b = 0.f;
#pragma unroll
    for (int k = 0; k < E_DIM; ++k) b = fmaf(xrow[k], emb[k * N_EMBED + j], b);
    return (a - 2.0f * b) + csum[j];
}

// a = np.sum(x*x, axis=1) replica (AVX512 pairwise), x in registers
__device__ __forceinline__ float a_np_of(const float* x) {
#pragma clang fp contract(off)
    float s[16];
#pragma unroll
    for (int i = 0; i < 16; ++i)
        s[i] = (x[i] * x[i] + x[i + 16] * x[i + 16]) +
               (x[i + 32] * x[i + 32] + x[i + 48] * x[i + 48]);
    float hh[8];
#pragma unroll
    for (int i = 0; i < 8; ++i) hh[i] = s[i] + s[i + 8];
    float uu[4];
#pragma unroll
    for (int i = 0; i < 4; ++i) uu[i] = hh[i] + hh[i + 4];
    return (uu[0] + uu[2]) + (uu[1] + uu[3]);
}

__device__ __forceinline__ bool lexless(float av, int ai, float bv, int bi) {
    return (av < bv) || (av == bv && ai < bi);
}

// merged prep: blocks 0-255: bf16 hi/lo of -2e into FRAGMENT-MAJOR layout
//   idx = chunk*16384 + frag*512 + lane*8 + j   (shorts)
//   chunk=n>>7; tp=(n&127)>>6; c_local=n&63; whichAB=c_local>>5; col=c_local&31
//   slot=k>>3; s=slot>>1; h=slot&1; j=k&7; lane=h*32+col
//   fragHi=(tp*4+s)*4+whichAB*2; fragLo=fragHi+1
// + embed copy + f32 transposed embT. Blocks 256-259: c_j sequential sum
// (reference replica); block 256 thread 0 zeroes the queue counter.
__global__ __launch_bounds__(256) void vq_prep(const float* __restrict__ emb,
                                               short* __restrict__ eTc,
                                               float* __restrict__ out_e,
                                               float* __restrict__ embT,
                                               float* __restrict__ c_out,
                                               unsigned int* __restrict__ qcnt) {
    const int b = blockIdx.x;
    if (b < 256) {
        const int t = b * 256 + threadIdx.x;   // t = k*1024 + n
        const int k = t >> 10, n = t & 1023;
        float e = emb[t];
        float m2 = -2.0f * e;
        short hb = f2bf_bits(m2);
        short lb = f2bf_bits(m2 - bfbits2f(hb));
        const int chunk = n >> 7;
        const int tp = (n & 127) >> 6;
        const int c_local = n & 63;
        const int whichAB = c_local >> 5, col = c_local & 31;
        const int slot = k >> 3, s = slot >> 1, h = slot & 1, j = k & 7;
        const int lane = h * 32 + col;
        const int fragHi = (tp * 4 + s) * 4 + whichAB * 2;
        const int base = chunk * 16384 + lane * 8 + j;
        eTc[base + fragHi * 512]       = hb;
        eTc[base + (fragHi + 1) * 512] = lb;
        out_e[t] = e;
        embT[n * E_DIM + k] = e;
    } else {
#pragma clang fp contract(off)
        if (b == 256 && threadIdx.x == 0) qcnt[0] = 0;
        const int j = (b - 256) * 256 + threadIdx.x;
        float e = emb[j];
        float s = e * e;
        for (int k = 1; k < E_DIM; ++k) {
            float ek = emb[k * N_EMBED + j];
            float pk = ek * ek;
            s = s + pk;
        }
        c_out[j] = s;
    }
}

// epilogue on raw acc (= c - 2b~ thanks to c-init): branchy top-3
__device__ __forceinline__ void tile_epilogue(
    const f32x16& acc, int codebase_global, int h,
    float& v1, float& v2, float& v3, int& i1, int& i2) {
#pragma unroll
    for (int r = 0; r < 16; ++r) {
        const int row = (r & 3) + 8 * (r >> 2) + 4 * h;
        const float d = acc[r];
        const int idx = codebase_global + row;
        if (d < v3) {
            if (d < v1)      { v3 = v2; v2 = v1; i2 = i1; v1 = d; i1 = idx; }
            else if (d < v2) { v3 = v2; v2 = d;  i2 = idx; }
            else             { v3 = d; }
        }
    }
}

__global__ __launch_bounds__(256, 4) void vq_screen_kernel(
    const float* __restrict__ in, const float* __restrict__ emb,
    const float* __restrict__ csum, const short* __restrict__ eTc,
    float* __restrict__ out_idx, float* __restrict__ out_in,
    unsigned int* __restrict__ qcnt, unsigned int* __restrict__ fullQ)
{
    const int t = threadIdx.x;
    const int wave = t >> 6, l = t & 63, col = l & 31, h = l >> 5;
    const int tok = blockIdx.x * 128 + wave * 32 + col;
    const float* xrow = in + (size_t)tok * E_DIM;
    const size_t obase = (size_t)tok * E_DIM;

    // ---- B operand (this lane's k-half): x[tok][s*16 + h*8 + j];
    // out_in written here (validated r13/r14: drains under the kernel).
    float xv[4][8];
#pragma unroll
    for (int s = 0; s < 4; ++s) {
        float4 u0 = *reinterpret_cast<const float4*>(xrow + s * 16 + h * 8);
        float4 u1 = *reinterpret_cast<const float4*>(xrow + s * 16 + h * 8 + 4);
        xv[s][0] = u0.x; xv[s][1] = u0.y; xv[s][2] = u0.z; xv[s][3] = u0.w;
        xv[s][4] = u1.x; xv[s][5] = u1.y; xv[s][6] = u1.z; xv[s][7] = u1.w;
        *reinterpret_cast<float4*>(out_in + obase + s * 16 + h * 8)     = u0;
        *reinterpret_cast<float4*>(out_in + obase + s * 16 + h * 8 + 4) = u1;
    }
    bf16x8 bhi[4], blo[4];
    float sax_h = 0.f;
#pragma unroll
    for (int s = 0; s < 4; ++s) {
#pragma unroll
        for (int j = 0; j < 8; ++j) {
            float x = xv[s][j];
            sax_h += fabsf(x);
            short hb = f2bf_bits(x);
            bhi[s][j] = hb;
            blo[s][j] = f2bf_bits(x - bfbits2f(hb));
        }
    }
    const float sax = sax_h + __shfl_xor(sax_h, 32, 64);

    // ---- exact a (AVX512-pairwise replica) via cross-half exchange
    float a_np;
    {
#pragma clang fp contract(off)
        float sv[8];
#pragma unroll
        for (int j = 0; j < 8; ++j) {
            float p0 = xv[0][j] * xv[0][j];
            float p1 = xv[1][j] * xv[1][j];
            float p2 = xv[2][j] * xv[2][j];
            float p3 = xv[3][j] * xv[3][j];
            sv[j] = (p0 + p1) + (p2 + p3);
        }
        float hh[8];
#pragma unroll
        for (int j = 0; j < 8; ++j) hh[j] = sv[j] + __shfl_xor(sv[j], 32, 64);
        float u0 = hh[0] + hh[4], u1 = hh[1] + hh[5];
        float u2 = hh[2] + hh[6], u3 = hh[3] + hh[7];
        a_np = (u0 + u2) + (u1 + u3);
    }

    // ---- top-3 trackers on v = c - 2b~ (ascending code order, strict <)
    float v1 = 3.4e38f, v2 = 3.4e38f, v3 = 3.4e38f;
    int i1 = 0, i2 = 0;

    // per-lane fragment base (shorts): lane*8; chunk stride 16384 shorts
    const short* gch = eTc + l * 8;

    for (int cc = 0; cc < 8; ++cc) {
        const int cb = cc << 7;
#pragma unroll
        for (int tp = 0; tp < 2; ++tp) {
            const int cbase = cb + tp * 64 + 4 * h;
            // acc initialized with c via MFMA C-operand (validated rounds 9-14)
            const float4 cA0 = *reinterpret_cast<const float4*>(&csum[cbase + 0]);
            const float4 cA1 = *reinterpret_cast<const float4*>(&csum[cbase + 8]);
            const float4 cA2 = *reinterpret_cast<const float4*>(&csum[cbase + 16]);
            const float4 cA3 = *reinterpret_cast<const float4*>(&csum[cbase + 24]);
            const float4 cB0 = *reinterpret_cast<const float4*>(&csum[cbase + 32]);
            const float4 cB1 = *reinterpret_cast<const float4*>(&csum[cbase + 40]);
            const float4 cB2 = *reinterpret_cast<const float4*>(&csum[cbase + 48]);
            const float4 cB3 = *reinterpret_cast<const float4*>(&csum[cbase + 56]);
            f32x16 accA, accB;
            accA[0]=cA0.x;  accA[1]=cA0.y;  accA[2]=cA0.z;  accA[3]=cA0.w;
            accA[4]=cA1.x;  accA[5]=cA1.y;  accA[6]=cA1.z;  accA[7]=cA1.w;
            accA[8]=cA2.x;  accA[9]=cA2.y;  accA[10]=cA2.z; accA[11]=cA2.w;
            accA[12]=cA3.x; accA[13]=cA3.y; accA[14]=cA3.z; accA[15]=cA3.w;
            accB[0]=cB0.x;  accB[1]=cB0.y;  accB[2]=cB0.z;  accB[3]=cB0.w;
            accB[4]=cB1.x;  accB[5]=cB1.y;  accB[6]=cB1.z;  accB[7]=cB1.w;
            accB[8]=cB2.x;  accB[9]=cB2.y;  accB[10]=cB2.z; accB[11]=cB2.w;
            accB[12]=cB3.x; accB[13]=cB3.y; accB[14]=cB3.z; accB[15]=cB3.w;
#pragma unroll
            for (int s = 0; s < 4; ++s) {
                // fragment-major direct L2 reads: one coalesced 16B/lane each
                const int fb = cc * 16384 + ((tp * 4 + s) * 4) * 512;
                const bf16x8 ahA = *reinterpret_cast<const bf16x8*>(gch + fb + 0 * 512);
                const bf16x8 alA = *reinterpret_cast<const bf16x8*>(gch + fb + 1 * 512);
                const bf16x8 ahB = *reinterpret_cast<const bf16x8*>(gch + fb + 2 * 512);
                const bf16x8 alB = *reinterpret_cast<const bf16x8*>(gch + fb + 3 * 512);
                accA = __builtin_amdgcn_mfma_f32_32x32x16_bf16(ahA, bhi[s], accA, 0, 0, 0);
                accB = __builtin_amdgcn_mfma_f32_32x32x16_bf16(ahB, bhi[s], accB, 0, 0, 0);
                accA = __builtin_amdgcn_mfma_f32_32x32x16_bf16(ahA, blo[s], accA, 0, 0, 0);
                accB = __builtin_amdgcn_mfma_f32_32x32x16_bf16(ahB, blo[s], accB, 0, 0, 0);
                accA = __builtin_amdgcn_mfma_f32_32x32x16_bf16(alA, bhi[s], accA, 0, 0, 0);
                accB = __builtin_amdgcn_mfma_f32_32x32x16_bf16(alB, bhi[s], accB, 0, 0, 0);
            }
            tile_epilogue(accA, cb + tp * 64,      h, v1, v2, v3, i1, i2);
            tile_epilogue(accB, cb + tp * 64 + 32, h, v1, v2, v3, i1, i2);
        }
    }

    // ---- merge the two k-halves (lanes l and l^32 hold complementary rows)
    const float w1 = __shfl_xor(v1, 32, 64), w2 = __shfl_xor(v2, 32, 64), w3 = __shfl_xor(v3, 32, 64);
    const int   j1 = __shfl_xor(i1, 32, 64), j2 = __shfl_xor(i2, 32, 64);
    const bool bfirst = lexless(w1, j1, v1, i1);
    const float r1v = bfirst ? w1 : v1;  const int r1i = bfirst ? j1 : i1;
    const float cav = bfirst ? v1 : v2;  const int cai = bfirst ? i1 : i2;
    const float cbv = bfirst ? w2 : w1;  const int cbi = bfirst ? j2 : j1;
    const bool bsec = lexless(cbv, cbi, cav, cai);
    const float r2v = bsec ? cbv : cav;  const int r2i = bsec ? cbi : cai;
    const float r3v = bsec ? fminf(cav, bfirst ? w3 : w2)
                           : fminf(cbv, bfirst ? v2 : v3);

    if (l < 32) {
        // 3-pass screen err ~5e-6 + reference fl(a-2b), fl(+c) double
        // rounding (<= 6.2e-5 for a<150); 1.3x margin (verified r8/10-14).
        const float thr = 8e-5f + 4e-7f * sax;
        const bool sane = (a_np < 150.f) && (sax < 128.f) && (fabsf(r1v) < 0.5f);
        int fin = r1i;
        if (sane && (r2v - r1v > thr)) {
            // certified: screen winner = reference argmin
        } else if (sane && (r3v - r1v > thr)) {
            // true argmin is one of {r1i, r2i}: exact pair resolve (lex tie)
            const float d1 = exact_d(xrow, emb, csum, a_np, r1i);
            const float d2 = exact_d(xrow, emb, csum, a_np, r2i);
            if (d2 < d1 || (d2 == d1 && r2i < r1i)) fin = r2i;
        } else {
            const unsigned int qi = atomicAdd(qcnt, 1u);
            if (qi < FQCAP) fullQ[qi] = (unsigned int)tok;
            // provisional fin = r1i; fallback overwrites
        }
        out_idx[tok] = (float)fin;
    }
}

// exact full rescan (reference replica) for 3-way ties / guard trips
__global__ __launch_bounds__(256) void vq_full_kernel(
    const float* __restrict__ in, const float* __restrict__ emb,
    const float* __restrict__ csum, const unsigned int* __restrict__ qcnt,
    const unsigned int* __restrict__ fullQ, float* __restrict__ out_idx) {
#pragma clang fp contract(off)
    unsigned int nq = *qcnt;
    if (nq > FQCAP) nq = FQCAP;
    const int l = threadIdx.x & 63;
    for (unsigned int w = blockIdx.x * 4 + (threadIdx.x >> 6); w < nq; w += 1024) {
        const int tok = (int)fullQ[w];
        const float* xrow = in + (size_t)tok * E_DIM;
        float x[E_DIM];
#pragma unroll
        for (int j4 = 0; j4 < 16; ++j4) {
            const float4 u = *reinterpret_cast<const float4*>(xrow + j4 * 4);
            x[j4 * 4 + 0] = u.x; x[j4 * 4 + 1] = u.y;
            x[j4 * 4 + 2] = u.z; x[j4 * 4 + 3] = u.w;
        }
        const float a = a_np_of(x);
        const int c0 = l * 16;
        float b[16];
#pragma unroll
        for (int q = 0; q < 16; ++q) b[q] = 0.f;
        for (int k = 0; k < E_DIM; ++k) {
            const float xk = x[k];
            const float* er = emb + k * N_EMBED + c0;
#pragma unroll
            for (int q = 0; q < 16; ++q) b[q] = fmaf(xk, er[q], b[q]);
        }
        float bd = 3.4e38f; int bi = 1 << 30;
#pragma unroll
        for (int q = 0; q < 16; ++q) {
            const float d = (a - 2.0f * b[q]) + csum[c0 + q];
            if (d < bd) { bd = d; bi = c0 + q; }
        }
        for (int m = 1; m < 64; m <<= 1) {
            const float od = __shfl_xor(bd, m, 64);
            const int oi = __shfl_xor(bi, m, 64);
            if (od < bd || (od == bd && oi < bi)) { bd = od; bi = oi; }
        }
        if (l == 0) out_idx[tok] = (float)bi;
    }
}

// quantize / straight-through grad (outputs 0,2); in-copy already written by
// the screen. q gathered as one float4 from the f32 transposed embT.
__global__ __launch_bounds__(256) void vq_gather_kernel(
    const float* __restrict__ in, const float* __restrict__ embT,
    const float* __restrict__ idxf,
    float* __restrict__ out_q, float* __restrict__ out_g) {
#pragma clang fp contract(off)
    const size_t j = (size_t)blockIdx.x * 256 + threadIdx.x;  // float4 index
    const int m  = (int)(j >> 4);
    const int k0 = ((int)j & 15) * 4;
    const int idx = (int)idxf[m];

    const float4 x = reinterpret_cast<const float4*>(in)[j];
    const float4 q = *reinterpret_cast<const float4*>(&embT[(size_t)idx * E_DIM + k0]);

    float4 g;
    g.x = x.x + (q.x - x.x);
    g.y = x.y + (q.y - x.y);
    g.z = x.z + (q.z - x.z);
    g.w = x.w + (q.w - x.w);

    reinterpret_cast<float4*>(out_q)[j] = q;
    reinterpret_cast<float4*>(out_g)[j] = g;
}

extern "C" void kernel_launch(void* const* d_in, const int* in_sizes, int n_in,
                              void* d_out, int out_size, void* d_ws, size_t ws_size,
                              hipStream_t stream) {
    const float* in  = (const float*)d_in[0];   // [262144, 64] f32
    const float* emb = (const float*)d_in[1];   // [64, 1024]  f32

    float* out     = (float*)d_out;
    float* out_q   = out;
    float* out_in  = out + (size_t)N_TOKENS * E_DIM;
    float* out_g   = out + 2ull * N_TOKENS * E_DIM;
    float* out_idx = out + 3ull * N_TOKENS * E_DIM;
    float* out_e   = out_idx + N_TOKENS;

    unsigned char* ws = (unsigned char*)d_ws;
    float*          c_ws  = (float*)(ws);                          // 4 KB
    short*          eTc   = (short*)(ws + 4096);                   // 256 KB
    float*          embT  = (float*)(ws + 4096 + 262144);          // 256 KB
    unsigned int*   qcnt  = (unsigned int*)(ws + 4096 + 262144 + 262144);  // 256 B
    unsigned int*   fullQ = (unsigned int*)(ws + 4096 + 262144 + 262144 + 256); // 128 KB

    vq_prep<<<260, 256, 0, stream>>>(emb, eTc, out_e, embT, c_ws, qcnt);

    vq_screen_kernel<<<N_TOKENS / 128, 256, 0, stream>>>(
        in, emb, c_ws, eTc, out_idx, out_in, qcnt, fullQ);

    vq_full_kernel<<<256, 256, 0, stream>>>(in, emb, c_ws, qcnt, fullQ, out_idx);

    const int gather_blocks = (N_TOKENS * E_DIM / 4) / 256;        // 16384
    vq_gather_kernel<<<gather_blocks, 256, 0, stream>>>(in, embT, out_idx,
                                                        out_q, out_g);
}

// Round 16
// 267.775 us; speedup vs baseline: 1.0681x; 1.0681x over previous
//
#include <hip/hip_runtime.h>
#include <hip/hip_bf16.h>
#include <math.h>

#define E_DIM    64
#define N_EMBED  1024
#define N_TOKENS 262144
#define FQCAP    32768

typedef __attribute__((ext_vector_type(8)))  short bf16x8;
typedef __attribute__((ext_vector_type(16))) float f32x16;

// ---------------------------------------------------------------------------
// Reference semantics (verified absmax 0.0 rounds 2,3,5,6,8-15): f32 numpy
// mirror:  b_j single fmaf chain ascending k;  a AVX512-pairwise;
// c_j sequential;  dist = fl(fl(a-2b)+c);  argmin first-min-wins.
// Round 16 = round 14 restored verbatim (measured best: 267.5 us).
// Search record since r10 (273.7): r11 pair-kernel eviction 306; r12 fused
// q/g @(256,4) 320 (acc spill); r13 fused + xv-kill 287; r14 in-copy-only
// fusion 267.5; r15 L2-direct fragments (no LDS) 286 (latency-bound).
// Conclusion: LDS-staged screen + separate q/g gather is the optimum of
// this structure; screen is mixed VALU/LDS/barrier-bound (MFMA 44 us vs
// 41 floor), not reducible further without disasm-level scheduling.
// ---------------------------------------------------------------------------

__device__ __forceinline__ short f2bf_bits(float f) {
    __hip_bfloat16 h = __float2bfloat16(f);
    return *reinterpret_cast<short*>(&h);
}
__device__ __forceinline__ float bfbits2f(short s) {
    unsigned int u = ((unsigned int)(unsigned short)s) << 16;
    return __uint_as_float(u);
}

// exact replica of one dist entry: d = fl(fl(a-2b)+c), b = fmaf chain asc k
__device__ __forceinline__ float exact_d(const float* __restrict__ xrow,
                                         const float* __restrict__ emb,
                                         const float* __restrict__ csum,
                                         float a, int j) {
#pragma clang fp contract(off)
    float b = 0.f;
#pragma unroll
    for (int k = 0; k < E_DIM; ++k) b = fmaf(xrow[k], emb[k * N_EMBED + j], b);
    return (a - 2.0f * b) + csum[j];
}

// a = np.sum(x*x, axis=1) replica (AVX512 pairwise), x in registers
__device__ __forceinline__ float a_np_of(const float* x) {
#pragma clang fp contract(off)
    float s[16];
#pragma unroll
    for (int i = 0; i < 16; ++i)
        s[i] = (x[i] * x[i] + x[i + 16] * x[i + 16]) +
               (x[i + 32] * x[i + 32] + x[i + 48] * x[i + 48]);
    float hh[8];
#pragma unroll
    for (int i = 0; i < 8; ++i) hh[i] = s[i] + s[i + 8];
    float uu[4];
#pragma unroll
    for (int i = 0; i < 4; ++i) uu[i] = hh[i] + hh[i + 4];
    return (uu[0] + uu[2]) + (uu[1] + uu[3]);
}

__device__ __forceinline__ bool lexless(float av, int ai, float bv, int bi) {
    return (av < bv) || (av == bv && ai < bi);
}

// merged prep: blocks 0-255: bf16 hi/lo of -2e into linear chunk layout
// [chunk][hi|lo][slot=k>>3][code][j=k&7] + embed copy + f32 transposed embT;
// blocks 256-259: c_j = sequential sum of e^2 (reference replica).
// Block 256 thread 0 also zeroes the fallback-queue counter.
__global__ __launch_bounds__(256) void vq_prep(const float* __restrict__ emb,
                                               short* __restrict__ eTc,
                                               float* __restrict__ out_e,
                                               float* __restrict__ embT,
                                               float* __restrict__ c_out,
                                               unsigned int* __restrict__ qcnt) {
    const int b = blockIdx.x;
    if (b < 256) {
        const int t = b * 256 + threadIdx.x;   // t = k*1024 + n
        const int k = t >> 10, n = t & 1023;
        float e = emb[t];
        float m2 = -2.0f * e;
        short hb = f2bf_bits(m2);
        short lb = f2bf_bits(m2 - bfbits2f(hb));
        const int chunk = n >> 7, code = n & 127, slot = k >> 3, jj = k & 7;
        const int base = chunk * 16384 + (slot * 128 + code) * 8 + jj;
        eTc[base]        = hb;
        eTc[base + 8192] = lb;
        out_e[t] = e;
        embT[n * E_DIM + k] = e;
    } else {
#pragma clang fp contract(off)
        if (b == 256 && threadIdx.x == 0) qcnt[0] = 0;
        const int j = (b - 256) * 256 + threadIdx.x;
        float e = emb[j];
        float s = e * e;
        for (int k = 1; k < E_DIM; ++k) {
            float ek = emb[k * N_EMBED + j];
            float pk = ek * ek;
            s = s + pk;
        }
        c_out[j] = s;
    }
}

// epilogue on raw acc (= c - 2b~ thanks to c-init): branchy top-3
__device__ __forceinline__ void tile_epilogue(
    const f32x16& acc, int codebase_global, int h,
    float& v1, float& v2, float& v3, int& i1, int& i2) {
#pragma unroll
    for (int r = 0; r < 16; ++r) {
        const int row = (r & 3) + 8 * (r >> 2) + 4 * h;
        const float d = acc[r];
        const int idx = codebase_global + row;
        if (d < v3) {
            if (d < v1)      { v3 = v2; v2 = v1; i2 = i1; v1 = d; i1 = idx; }
            else if (d < v2) { v3 = v2; v2 = d;  i2 = idx; }
            else             { v3 = d; }
        }
    }
}

__global__ __launch_bounds__(256, 4) void vq_screen_kernel(
    const float* __restrict__ in, const float* __restrict__ emb,
    const float* __restrict__ csum, const short* __restrict__ eTc,
    float* __restrict__ out_idx, float* __restrict__ out_in,
    unsigned int* __restrict__ qcnt, unsigned int* __restrict__ fullQ)
{
    __shared__ uint4 lds_e[2048];   // [0..1024) hi, [1024..2048) lo ; 32 KB

    const int t = threadIdx.x;
    const int wave = t >> 6, l = t & 63, col = l & 31, h = l >> 5;
    const int tok = blockIdx.x * 128 + wave * 32 + col;
    const float* xrow = in + (size_t)tok * E_DIM;
    const size_t obase = (size_t)tok * E_DIM;

    // ---- B operand (this lane's k-half): x[tok][s*16 + h*8 + j];
    // out_in written here (validated r13/r14: no live-range extension,
    // writes drain under the whole kernel; screen HBM only ~8% busy).
    float xv[4][8];
#pragma unroll
    for (int s = 0; s < 4; ++s) {
        float4 u0 = *reinterpret_cast<const float4*>(xrow + s * 16 + h * 8);
        float4 u1 = *reinterpret_cast<const float4*>(xrow + s * 16 + h * 8 + 4);
        xv[s][0] = u0.x; xv[s][1] = u0.y; xv[s][2] = u0.z; xv[s][3] = u0.w;
        xv[s][4] = u1.x; xv[s][5] = u1.y; xv[s][6] = u1.z; xv[s][7] = u1.w;
        *reinterpret_cast<float4*>(out_in + obase + s * 16 + h * 8)     = u0;
        *reinterpret_cast<float4*>(out_in + obase + s * 16 + h * 8 + 4) = u1;
    }
    bf16x8 bhi[4], blo[4];
    float sax_h = 0.f;
#pragma unroll
    for (int s = 0; s < 4; ++s) {
#pragma unroll
        for (int j = 0; j < 8; ++j) {
            float x = xv[s][j];
            sax_h += fabsf(x);
            short hb = f2bf_bits(x);
            bhi[s][j] = hb;
            blo[s][j] = f2bf_bits(x - bfbits2f(hb));
        }
    }
    const float sax = sax_h + __shfl_xor(sax_h, 32, 64);

    // ---- exact a (AVX512-pairwise replica) via cross-half exchange
    float a_np;
    {
#pragma clang fp contract(off)
        float sv[8];
#pragma unroll
        for (int j = 0; j < 8; ++j) {
            float p0 = xv[0][j] * xv[0][j];
            float p1 = xv[1][j] * xv[1][j];
            float p2 = xv[2][j] * xv[2][j];
            float p3 = xv[3][j] * xv[3][j];
            sv[j] = (p0 + p1) + (p2 + p3);
        }
        float hh[8];
#pragma unroll
        for (int j = 0; j < 8; ++j) hh[j] = sv[j] + __shfl_xor(sv[j], 32, 64);
        float u0 = hh[0] + hh[4], u1 = hh[1] + hh[5];
        float u2 = hh[2] + hh[6], u3 = hh[3] + hh[7];
        a_np = (u0 + u2) + (u1 + u3);
    }

    // ---- top-3 trackers on v = c - 2b~ (ascending code order, strict <)
    float v1 = 3.4e38f, v2 = 3.4e38f, v3 = 3.4e38f;
    int i1 = 0, i2 = 0;

    for (int cc = 0; cc < 8; ++cc) {
        __syncthreads();
        {   // linear 32 KB copy: coalesced global reads, linear b128 LDS writes
            const uint4* gsrc = reinterpret_cast<const uint4*>(eTc) + cc * 2048;
#pragma unroll
            for (int j = 0; j < 8; ++j) lds_e[j * 256 + t] = gsrc[j * 256 + t];
        }
        __syncthreads();

        const int cb = cc << 7;
#pragma unroll
        for (int tp = 0; tp < 2; ++tp) {
            const int c0 = tp * 64 + col;
            const int cbase = cb + tp * 64 + 4 * h;
            // acc initialized with c via MFMA C-operand (validated rounds 9-14)
            const float4 cA0 = *reinterpret_cast<const float4*>(&csum[cbase + 0]);
            const float4 cA1 = *reinterpret_cast<const float4*>(&csum[cbase + 8]);
            const float4 cA2 = *reinterpret_cast<const float4*>(&csum[cbase + 16]);
            const float4 cA3 = *reinterpret_cast<const float4*>(&csum[cbase + 24]);
            const float4 cB0 = *reinterpret_cast<const float4*>(&csum[cbase + 32]);
            const float4 cB1 = *reinterpret_cast<const float4*>(&csum[cbase + 40]);
            const float4 cB2 = *reinterpret_cast<const float4*>(&csum[cbase + 48]);
            const float4 cB3 = *reinterpret_cast<const float4*>(&csum[cbase + 56]);
            f32x16 accA, accB;
            accA[0]=cA0.x;  accA[1]=cA0.y;  accA[2]=cA0.z;  accA[3]=cA0.w;
            accA[4]=cA1.x;  accA[5]=cA1.y;  accA[6]=cA1.z;  accA[7]=cA1.w;
            accA[8]=cA2.x;  accA[9]=cA2.y;  accA[10]=cA2.z; accA[11]=cA2.w;
            accA[12]=cA3.x; accA[13]=cA3.y; accA[14]=cA3.z; accA[15]=cA3.w;
            accB[0]=cB0.x;  accB[1]=cB0.y;  accB[2]=cB0.z;  accB[3]=cB0.w;
            accB[4]=cB1.x;  accB[5]=cB1.y;  accB[6]=cB1.z;  accB[7]=cB1.w;
            accB[8]=cB2.x;  accB[9]=cB2.y;  accB[10]=cB2.z; accB[11]=cB2.w;
            accB[12]=cB3.x; accB[13]=cB3.y; accB[14]=cB3.z; accB[15]=cB3.w;
#pragma unroll
            for (int s = 0; s < 4; ++s) {
                const int slot = 2 * s + h;
                bf16x8 ahA = *reinterpret_cast<const bf16x8*>(&lds_e[slot * 128 + c0]);
                bf16x8 alA = *reinterpret_cast<const bf16x8*>(&lds_e[1024 + slot * 128 + c0]);
                bf16x8 ahB = *reinterpret_cast<const bf16x8*>(&lds_e[slot * 128 + c0 + 32]);
                bf16x8 alB = *reinterpret_cast<const bf16x8*>(&lds_e[1024 + slot * 128 + c0 + 32]);
                accA = __builtin_amdgcn_mfma_f32_32x32x16_bf16(ahA, bhi[s], accA, 0, 0, 0);
                accB = __builtin_amdgcn_mfma_f32_32x32x16_bf16(ahB, bhi[s], accB, 0, 0, 0);
                accA = __builtin_amdgcn_mfma_f32_32x32x16_bf16(ahA, blo[s], accA, 0, 0, 0);
                accB = __builtin_amdgcn_mfma_f32_32x32x16_bf16(ahB, blo[s], accB, 0, 0, 0);
                accA = __builtin_amdgcn_mfma_f32_32x32x16_bf16(alA, bhi[s], accA, 0, 0, 0);
                accB = __builtin_amdgcn_mfma_f32_32x32x16_bf16(alB, bhi[s], accB, 0, 0, 0);
            }
            tile_epilogue(accA, cb + tp * 64,      h, v1, v2, v3, i1, i2);
            tile_epilogue(accB, cb + tp * 64 + 32, h, v1, v2, v3, i1, i2);
        }
    }

    // ---- merge the two k-halves (lanes l and l^32 hold complementary rows)
    const float w1 = __shfl_xor(v1, 32, 64), w2 = __shfl_xor(v2, 32, 64), w3 = __shfl_xor(v3, 32, 64);
    const int   j1 = __shfl_xor(i1, 32, 64), j2 = __shfl_xor(i2, 32, 64);
    const bool bfirst = lexless(w1, j1, v1, i1);
    const float r1v = bfirst ? w1 : v1;  const int r1i = bfirst ? j1 : i1;
    const float cav = bfirst ? v1 : v2;  const int cai = bfirst ? i1 : i2;
    const float cbv = bfirst ? w2 : w1;  const int cbi = bfirst ? j2 : j1;
    const bool bsec = lexless(cbv, cbi, cav, cai);
    const float r2v = bsec ? cbv : cav;  const int r2i = bsec ? cbi : cai;
    const float r3v = bsec ? fminf(cav, bfirst ? w3 : w2)
                           : fminf(cbv, bfirst ? v2 : v3);

    if (l < 32) {
        // 3-pass screen err ~5e-6 + reference fl(a-2b), fl(+c) double
        // rounding (<= 6.2e-5 for a<150); 1.3x margin (verified r8/10-15).
        const float thr = 8e-5f + 4e-7f * sax;
        const bool sane = (a_np < 150.f) && (sax < 128.f) && (fabsf(r1v) < 0.5f);
        int fin = r1i;
        if (sane && (r2v - r1v > thr)) {
            // certified: screen winner = reference argmin
        } else if (sane && (r3v - r1v > thr)) {
            // true argmin is one of {r1i, r2i}: exact pair resolve (lex tie)
            const float d1 = exact_d(xrow, emb, csum, a_np, r1i);
            const float d2 = exact_d(xrow, emb, csum, a_np, r2i);
            if (d2 < d1 || (d2 == d1 && r2i < r1i)) fin = r2i;
        } else {
            const unsigned int qi = atomicAdd(qcnt, 1u);
            if (qi < FQCAP) fullQ[qi] = (unsigned int)tok;
            // provisional fin = r1i; fallback overwrites
        }
        out_idx[tok] = (float)fin;
    }
}

// exact full rescan (reference replica) for 3-way ties / guard trips
__global__ __launch_bounds__(256) void vq_full_kernel(
    const float* __restrict__ in, const float* __restrict__ emb,
    const float* __restrict__ csum, const unsigned int* __restrict__ qcnt,
    const unsigned int* __restrict__ fullQ, float* __restrict__ out_idx) {
#pragma clang fp contract(off)
    unsigned int nq = *qcnt;
    if (nq > FQCAP) nq = FQCAP;
    const int l = threadIdx.x & 63;
    for (unsigned int w = blockIdx.x * 4 + (threadIdx.x >> 6); w < nq; w += 1024) {
        const int tok = (int)fullQ[w];
        const float* xrow = in + (size_t)tok * E_DIM;
        float x[E_DIM];
#pragma unroll
        for (int j4 = 0; j4 < 16; ++j4) {
            const float4 u = *reinterpret_cast<const float4*>(xrow + j4 * 4);
            x[j4 * 4 + 0] = u.x; x[j4 * 4 + 1] = u.y;
            x[j4 * 4 + 2] = u.z; x[j4 * 4 + 3] = u.w;
        }
        const float a = a_np_of(x);
        const int c0 = l * 16;
        float b[16];
#pragma unroll
        for (int q = 0; q < 16; ++q) b[q] = 0.f;
        for (int k = 0; k < E_DIM; ++k) {
            const float xk = x[k];
            const float* er = emb + k * N_EMBED + c0;
#pragma unroll
            for (int q = 0; q < 16; ++q) b[q] = fmaf(xk, er[q], b[q]);
        }
        float bd = 3.4e38f; int bi = 1 << 30;
#pragma unroll
        for (int q = 0; q < 16; ++q) {
            const float d = (a - 2.0f * b[q]) + csum[c0 + q];
            if (d < bd) { bd = d; bi = c0 + q; }
        }
        for (int m = 1; m < 64; m <<= 1) {
            const float od = __shfl_xor(bd, m, 64);
            const int oi = __shfl_xor(bi, m, 64);
            if (od < bd || (od == bd && oi < bi)) { bd = od; bi = oi; }
        }
        if (l == 0) out_idx[tok] = (float)bi;
    }
}

// quantize / straight-through grad (outputs 0,2); in-copy already written by
// the screen. q gathered as one float4 from the f32 transposed embT.
__global__ __launch_bounds__(256) void vq_gather_kernel(
    const float* __restrict__ in, const float* __restrict__ embT,
    const float* __restrict__ idxf,
    float* __restrict__ out_q, float* __restrict__ out_g) {
#pragma clang fp contract(off)
    const size_t j = (size_t)blockIdx.x * 256 + threadIdx.x;  // float4 index
    const int m  = (int)(j >> 4);
    const int k0 = ((int)j & 15) * 4;
    const int idx = (int)idxf[m];

    const float4 x = reinterpret_cast<const float4*>(in)[j];
    const float4 q = *reinterpret_cast<const float4*>(&embT[(size_t)idx * E_DIM + k0]);

    float4 g;
    g.x = x.x + (q.x - x.x);
    g.y = x.y + (q.y - x.y);
    g.z = x.z + (q.z - x.z);
    g.w = x.w + (q.w - x.w);

    reinterpret_cast<float4*>(out_q)[j] = q;
    reinterpret_cast<float4*>(out_g)[j] = g;
}

extern "C" void kernel_launch(void* const* d_in, const int* in_sizes, int n_in,
                              void* d_out, int out_size, void* d_ws, size_t ws_size,
                              hipStream_t stream) {
    const float* in  = (const float*)d_in[0];   // [262144, 64] f32
    const float* emb = (const float*)d_in[1];   // [64, 1024]  f32

    float* out     = (float*)d_out;
    float* out_q   = out;
    float* out_in  = out + (size_t)N_TOKENS * E_DIM;
    float* out_g   = out + 2ull * N_TOKENS * E_DIM;
    float* out_idx = out + 3ull * N_TOKENS * E_DIM;
    float* out_e   = out_idx + N_TOKENS;

    unsigned char* ws = (unsigned char*)d_ws;
    float*          c_ws  = (float*)(ws);                          // 4 KB
    short*          eTc   = (short*)(ws + 4096);                   // 256 KB
    float*          embT  = (float*)(ws + 4096 + 262144);          // 256 KB
    unsigned int*   qcnt  = (unsigned int*)(ws + 4096 + 262144 + 262144);  // 256 B
    unsigned int*   fullQ = (unsigned int*)(ws + 4096 + 262144 + 262144 + 256); // 128 KB

    vq_prep<<<260, 256, 0, stream>>>(emb, eTc, out_e, embT, c_ws, qcnt);

    vq_screen_kernel<<<N_TOKENS / 128, 256, 0, stream>>>(
        in, emb, c_ws, eTc, out_idx, out_in, qcnt, fullQ);

    vq_full_kernel<<<256, 256, 0, stream>>>(in, emb, c_ws, qcnt, fullQ, out_idx);

    const int gather_blocks = (N_TOKENS * E_DIM / 4) / 256;        // 16384
    vq_gather_kernel<<<gather_blocks, 256, 0, stream>>>(in, embT, out_idx,
                                                        out_q, out_g);
}